// Round 6
// baseline (740.711 us; speedup 1.0000x reference)
//
#include <hip/hip_runtime.h>

#define NNODES 102400
#define NBATCH 256
#define LSEQ   400
#define HS     256
#define KDIM   640
#define OC     128
#define NTAP   15
#define H1     512
#define STILE  80    // 5 * 80 = 400 exact
#define GR     96    // gemm rows per block: 80 + 14 halo + 2 (16-align)

typedef __attribute__((ext_vector_type(8))) short short8;
typedef __attribute__((ext_vector_type(4))) float floatx4;

__device__ inline unsigned short f2bf(float f) {
    unsigned u = __builtin_bit_cast(unsigned, f);
    unsigned r = (u + 0x7FFFu + ((u >> 16) & 1u)) >> 16;
    return (unsigned short)r;
}

// ------- fused setup: conv-kernel combine, weight packs, A_acc zero --------
// (zero_pads gone: seq buffer no longer exists)
__global__ __launch_bounds__(256) void setup_all(
    const float* __restrict__ k7, const float* __restrict__ k11,
    const float* __restrict__ k15, const float* __restrict__ cb7,
    const float* __restrict__ cb11, const float* __restrict__ cb15,
    const float* __restrict__ W_le, const float* __restrict__ Wl1,
    unsigned short* __restrict__ Wpk, float* __restrict__ bc,
    unsigned short* __restrict__ Wle_pk, unsigned short* __restrict__ Wl1_pk,
    float* __restrict__ A_acc)
{
    int bid = blockIdx.x, tid = threadIdx.x;
    if (bid < 1920) {
        // combine k7/k11/k15 (+/3) into one 15-tap weight, MFMA B-frag order
        int idx = bid * 256 + tid;                 // 15*256*128 = 491520 exact
        int oc = idx & (OC - 1);
        int ic = (idx >> 7) & (HS - 1);
        int d  = idx / (OC * HS);
        float wv = k15[(oc * HS + ic) * 15 + d];
        int t11 = d - 2;
        if (t11 >= 0 && t11 < 11) wv += k11[(oc * HS + ic) * 11 + t11];
        int t7 = d - 4;
        if (t7 >= 0 && t7 < 7)   wv += k7[(oc * HS + ic) * 7 + t7];
        wv *= (1.0f / 3.0f);
        int kc = ic >> 6, ks = (ic >> 5) & 1, qq = (ic >> 3) & 3, j = ic & 7;
        int nt = oc >> 4, n = oc & 15;
        int pidx = ((((d * 4 + kc) * 2 + ks) * 8 + nt) * 64 + (qq * 16 + n)) * 8 + j;
        Wpk[pidx] = f2bf(wv);
        if (idx < OC) bc[idx] = (cb7[idx] + cb11[idx] + cb15[idx]) * (1.0f / 3.0f);
    } else if (bid < 2560) {
        // pack W_le [640][256] -> bf16 fragment order (10 stages of BK=64)
        int idx = (bid - 1920) * 256 + tid;        // 640*256 = 640 blocks
        int k = idx >> 8, col = idx & 255;
        int t = k >> 6, ks = (k >> 5) & 1, qq = (k >> 3) & 3, j = k & 7;
        int nt = col >> 4, n = col & 15;
        int pidx = (((t * 2 + ks) * 16 + nt) * 64 + (qq * 16 + n)) * 8 + j;
        Wle_pk[pidx] = f2bf(W_le[k * 256 + col]);
    } else if (bid < 2816) {
        // pack Wl1 [128][512] -> bf16 fragment order (4 j-blocks of 128)
        int idx = (bid - 2560) * 256 + tid;        // 128*512 = 256 blocks
        int k = idx >> 9, col = idx & 511;
        int ks = k >> 5, qq = (k >> 3) & 3, j = k & 7;
        int jbb = col >> 7, nhnt = (col >> 4) & 7, n = col & 15;
        int pidx = jbb * 16384 + ((ks * 8 + nhnt) * 64 + (qq * 16 + n)) * 8 + j;
        Wl1_pk[pidx] = f2bf(Wl1[k * 512 + col]);
    } else {
        // zero A_acc: 256*512 f32 = 32768 float4 = 128 blocks
        int idx = (bid - 2816) * 256 + tid;
        ((float4*)A_acc)[idx] = make_float4(0.f, 0.f, 0.f, 0.f);
    }
}

// ------- fused main: per (b, s0) block computes its own 96-row GEMM tile
// (relu(emb@W_le+b_le) mixed with token embedding) directly into the LDS
// conv-input tile, then conv (implicit GEMM, 15 taps) -> kh-reduce ->
// fused MLP1 colsum -> atomicAdd A_acc. seq HBM round trip eliminated.
// Strides: Ag 76 shorts (152 B, dw-stride 38==6 mod 32 -> ~2-way banks),
// As 268 shorts (536 B, dw 134==6 mod 32) vs old 72/264 (==4 mod 32, 8-way).
union FusedSm {
    struct {
        unsigned short As[GR][268];      // 51456 B conv input tile
        unsigned short Ag[2][GR][76];    // 29184 B gemm A double buffer
    } g;                                  // 80640 B -> 2 blocks/CU
    struct {
        float red[40 * 132];              // 21120 B (half kh-reduction)
        unsigned short abf[STILE][136];   // 21760 B (mlp A-tile)
    } p2;
};

__device__ __forceinline__ void conv_load_Bh(
    const short8* __restrict__ wb, int h, int kh, int nh, int lane, short8 bf[4])
{
    int cc = h >> 1, ks = h & 1;
    int d = cc >> 1, kc = kh * 2 + (cc & 1);
    const short8* bp = wb + (size_t)(d * 4 + kc) * 1024 + nh * 256 + ks * 512 + lane;
    #pragma unroll
    for (int nt = 0; nt < 4; nt++)
        bf[nt] = bp[nt * 64];
}

__device__ __forceinline__ void conv_mfma_half(
    const unsigned short (*As)[268], floatx4 acc[5][4],
    const short8 bf[4], int h, int kh, int m, int q)
{
    int cc = h >> 1, ks = h & 1;
    int d = cc >> 1, kc = kh * 2 + (cc & 1);
    #pragma unroll
    for (int mt = 0; mt < 5; mt++) {
        short8 a = *(const short8*)&As[mt * 16 + m + d][kc * 64 + ks * 32 + q * 8];
        #pragma unroll
        for (int nt = 0; nt < 4; nt++)
            acc[mt][nt] = __builtin_amdgcn_mfma_f32_16x16x32_bf16(a, bf[nt], acc[mt][nt], 0, 0, 0);
    }
}

__global__ __launch_bounds__(256, 2) void fused_main(
    const float* __restrict__ emb, const int* __restrict__ x_tokens,
    const float* __restrict__ emb_table,
    const unsigned short* __restrict__ Wle_pk, const float* __restrict__ b_le,
    const unsigned short* __restrict__ Wpk, const float* __restrict__ bc,
    const unsigned short* __restrict__ Wl1_pk, const float* __restrict__ bl1,
    float* __restrict__ A_acc)
{
    __shared__ __align__(16) FusedSm sm;

    int b  = blockIdx.y;
    int s0 = blockIdx.x * STILE;               // 0,80,160,240,320
    int tid = threadIdx.x;
    int w = tid >> 6, lane = tid & 63;
    int q = lane >> 4, m = lane & 15;

    // ===================== phase 1: GEMM 96 x 256, K = 640 =================
    // Tile row r <-> sequence position p = s0 - 7 + r (conv halo included).
    // Invalid p (outside [0,400)) -> zero rows (the old zero-padding).
    int br = tid >> 4;          // staging row base 0..15
    int c  = tid & 15;          // staging float4 chunk 0..15
    const float4* pA[6];
    bool vld[6];
    #pragma unroll
    for (int u = 0; u < 6; u++) {
        int p = s0 - 7 + br + 16 * u;
        vld[u] = (p >= 0) && (p < LSEQ);
        int safe = vld[u] ? p : 0;
        pA[u] = (const float4*)&emb[(size_t)(b * LSEQ + safe) * KDIM];
    }

    const short8* wle = (const short8*)Wle_pk;
    float4 fA[6], fB[6];
    // prologue: stage0 -> fA, stage1 -> fB in flight; write stage0 to Ag[0]
    #pragma unroll
    for (int u = 0; u < 6; u++) fA[u] = pA[u][c];
    #pragma unroll
    for (int u = 0; u < 6; u++) fB[u] = pA[u][16 + c];
    #pragma unroll
    for (int u = 0; u < 6; u++) {
        float4 f = fA[u];
        ushort4 h;
        h.x = vld[u] ? f2bf(f.x) : (unsigned short)0;
        h.y = vld[u] ? f2bf(f.y) : (unsigned short)0;
        h.z = vld[u] ? f2bf(f.z) : (unsigned short)0;
        h.w = vld[u] ? f2bf(f.w) : (unsigned short)0;
        *(ushort4*)&sm.g.Ag[0][br + 16 * u][c * 4] = h;
    }
    asm volatile("s_waitcnt lgkmcnt(0)" ::: "memory");
    __builtin_amdgcn_s_barrier();

    floatx4 acc[6][4] = {};    // 96 rows x 64 cols per wave (N-strip w)
    for (int tt = 0; tt < 10; tt += 2) {
        // ---- even stage t=tt: MFMA Ag[0]; prefetch A(t+2)->fA; write fB->Ag[1]
        {
            const int t = tt;
            short8 bf[8];
            #pragma unroll
            for (int ks = 0; ks < 2; ks++)
                #pragma unroll
                for (int nt = 0; nt < 4; nt++)
                    bf[ks * 4 + nt] = wle[(size_t)t * 2048 + ks * 1024 + (w * 4 + nt) * 64 + lane];
            if (t + 2 < 10) {
                #pragma unroll
                for (int u = 0; u < 6; u++) fA[u] = pA[u][(t + 2) * 16 + c];
            }
            #pragma unroll
            for (int ks = 0; ks < 2; ks++) {
                short8 a0 = *(const short8*)&sm.g.Ag[0][ 0 + m][ks * 32 + q * 8];
                short8 a1 = *(const short8*)&sm.g.Ag[0][16 + m][ks * 32 + q * 8];
                short8 a2 = *(const short8*)&sm.g.Ag[0][32 + m][ks * 32 + q * 8];
                short8 a3 = *(const short8*)&sm.g.Ag[0][48 + m][ks * 32 + q * 8];
                short8 a4 = *(const short8*)&sm.g.Ag[0][64 + m][ks * 32 + q * 8];
                short8 a5 = *(const short8*)&sm.g.Ag[0][80 + m][ks * 32 + q * 8];
                #pragma unroll
                for (int nt = 0; nt < 4; nt++) {
                    short8 bv = bf[ks * 4 + nt];
                    acc[0][nt] = __builtin_amdgcn_mfma_f32_16x16x32_bf16(a0, bv, acc[0][nt], 0, 0, 0);
                    acc[1][nt] = __builtin_amdgcn_mfma_f32_16x16x32_bf16(a1, bv, acc[1][nt], 0, 0, 0);
                    acc[2][nt] = __builtin_amdgcn_mfma_f32_16x16x32_bf16(a2, bv, acc[2][nt], 0, 0, 0);
                    acc[3][nt] = __builtin_amdgcn_mfma_f32_16x16x32_bf16(a3, bv, acc[3][nt], 0, 0, 0);
                    acc[4][nt] = __builtin_amdgcn_mfma_f32_16x16x32_bf16(a4, bv, acc[4][nt], 0, 0, 0);
                    acc[5][nt] = __builtin_amdgcn_mfma_f32_16x16x32_bf16(a5, bv, acc[5][nt], 0, 0, 0);
                }
            }
            if (t + 1 < 10) {
                #pragma unroll
                for (int u = 0; u < 6; u++) {
                    float4 f = fB[u];
                    ushort4 h;
                    h.x = vld[u] ? f2bf(f.x) : (unsigned short)0;
                    h.y = vld[u] ? f2bf(f.y) : (unsigned short)0;
                    h.z = vld[u] ? f2bf(f.z) : (unsigned short)0;
                    h.w = vld[u] ? f2bf(f.w) : (unsigned short)0;
                    *(ushort4*)&sm.g.Ag[1][br + 16 * u][c * 4] = h;
                }
            }
            asm volatile("s_waitcnt lgkmcnt(0)" ::: "memory");
            __builtin_amdgcn_s_barrier();
        }
        // ---- odd stage t=tt+1: MFMA Ag[1]; prefetch A(t+2)->fB; write fA->Ag[0]
        {
            const int t = tt + 1;
            short8 bf[8];
            #pragma unroll
            for (int ks = 0; ks < 2; ks++)
                #pragma unroll
                for (int nt = 0; nt < 4; nt++)
                    bf[ks * 4 + nt] = wle[(size_t)t * 2048 + ks * 1024 + (w * 4 + nt) * 64 + lane];
            if (t + 2 < 10) {
                #pragma unroll
                for (int u = 0; u < 6; u++) fB[u] = pA[u][(t + 2) * 16 + c];
            }
            #pragma unroll
            for (int ks = 0; ks < 2; ks++) {
                short8 a0 = *(const short8*)&sm.g.Ag[1][ 0 + m][ks * 32 + q * 8];
                short8 a1 = *(const short8*)&sm.g.Ag[1][16 + m][ks * 32 + q * 8];
                short8 a2 = *(const short8*)&sm.g.Ag[1][32 + m][ks * 32 + q * 8];
                short8 a3 = *(const short8*)&sm.g.Ag[1][48 + m][ks * 32 + q * 8];
                short8 a4 = *(const short8*)&sm.g.Ag[1][64 + m][ks * 32 + q * 8];
                short8 a5 = *(const short8*)&sm.g.Ag[1][80 + m][ks * 32 + q * 8];
                #pragma unroll
                for (int nt = 0; nt < 4; nt++) {
                    short8 bv = bf[ks * 4 + nt];
                    acc[0][nt] = __builtin_amdgcn_mfma_f32_16x16x32_bf16(a0, bv, acc[0][nt], 0, 0, 0);
                    acc[1][nt] = __builtin_amdgcn_mfma_f32_16x16x32_bf16(a1, bv, acc[1][nt], 0, 0, 0);
                    acc[2][nt] = __builtin_amdgcn_mfma_f32_16x16x32_bf16(a2, bv, acc[2][nt], 0, 0, 0);
                    acc[3][nt] = __builtin_amdgcn_mfma_f32_16x16x32_bf16(a3, bv, acc[3][nt], 0, 0, 0);
                    acc[4][nt] = __builtin_amdgcn_mfma_f32_16x16x32_bf16(a4, bv, acc[4][nt], 0, 0, 0);
                    acc[5][nt] = __builtin_amdgcn_mfma_f32_16x16x32_bf16(a5, bv, acc[5][nt], 0, 0, 0);
                }
            }
            if (t + 1 < 10) {
                #pragma unroll
                for (int u = 0; u < 6; u++) {
                    float4 f = fA[u];
                    ushort4 h;
                    h.x = vld[u] ? f2bf(f.x) : (unsigned short)0;
                    h.y = vld[u] ? f2bf(f.y) : (unsigned short)0;
                    h.z = vld[u] ? f2bf(f.z) : (unsigned short)0;
                    h.w = vld[u] ? f2bf(f.w) : (unsigned short)0;
                    *(ushort4*)&sm.g.Ag[0][br + 16 * u][c * 4] = h;
                }
            }
            asm volatile("s_waitcnt lgkmcnt(0)" ::: "memory");
            __builtin_amdgcn_s_barrier();
        }
    }

    // gemm epilogue: bias + relu + 0.5*(. + token_emb) -> bf16 conv tile As.
    // Waves write disjoint column strips; invalid p rows -> zero (padding).
    #pragma unroll
    for (int mt = 0; mt < 6; mt++) {
        #pragma unroll
        for (int r = 0; r < 4; r++) {
            int row = mt * 16 + q * 4 + r;
            int p = s0 - 7 + row;
            bool v = (p >= 0) && (p < LSEQ);
            int tokb = v ? (x_tokens[b * LSEQ + p] * HS) : 0;
            #pragma unroll
            for (int nt = 0; nt < 4; nt++) {
                int col = w * 64 + nt * 16 + m;
                float vv = acc[mt][nt][r] + b_le[col];
                vv = vv > 0.f ? vv : 0.f;
                vv = 0.5f * (vv + emb_table[tokb + col]);
                sm.g.As[row][col] = v ? f2bf(vv) : (unsigned short)0;
            }
        }
    }
    // conv B prefetch overlaps the epilogue drain
    int nh = w >> 1, kh = w & 1;
    const short8* wb = (const short8*)Wpk;
    short8 bA[4], bB[4];
    conv_load_Bh(wb, 0, kh, nh, lane, bA);
    __syncthreads();

    // ===================== phase 2: conv implicit-GEMM =====================
    floatx4 acc3[5][4] = {};   // 80 s x 64 oc partial (this wave's ic-half)
    for (int h = 0; h < 60; h += 2) {
        conv_load_Bh(wb, h + 1, kh, nh, lane, bB);
        conv_mfma_half(sm.g.As, acc3, bA, h, kh, m, q);
        if (h + 2 < 60) conv_load_Bh(wb, h + 2, kh, nh, lane, bA);
        conv_mfma_half(sm.g.As, acc3, bB, h + 1, kh, m, q);
    }

    // ---- kh-pair reduce + bias + bf16 in two 40-row halves ----------------
    float bc0 = bc[lane * 2], bc1 = bc[lane * 2 + 1];
    __syncthreads();                       // all As reads done; alias as p2
    #pragma unroll
    for (int hh = 0; hh < 2; hh++) {
        if (kh == 1) {
            #pragma unroll
            for (int mt = 0; mt < 5; mt++)
                #pragma unroll
                for (int nt = 0; nt < 4; nt++)
                    #pragma unroll
                    for (int r = 0; r < 4; r++) {
                        int row = mt * 16 + q * 4 + r;
                        if (row >= hh * 40 && row < hh * 40 + 40)
                            sm.p2.red[(row - hh * 40) * 132 + nh * 64 + nt * 16 + m] = acc3[mt][nt][r];
                    }
        }
        __syncthreads();
        if (kh == 0) {
            #pragma unroll
            for (int mt = 0; mt < 5; mt++)
                #pragma unroll
                for (int nt = 0; nt < 4; nt++)
                    #pragma unroll
                    for (int r = 0; r < 4; r++) {
                        int row = mt * 16 + q * 4 + r;
                        if (row >= hh * 40 && row < hh * 40 + 40)
                            sm.p2.red[(row - hh * 40) * 132 + nh * 64 + nt * 16 + m] += acc3[mt][nt][r];
                    }
        }
        __syncthreads();
        // convert 40 rows: each wave 10 rows
        #pragma unroll
        for (int rr = 0; rr < 10; rr++) {
            int lrow = w * 10 + rr;
            float2 v = *(const float2*)&sm.p2.red[lrow * 132 + lane * 2];
            unsigned uo = (unsigned)f2bf(v.x + bc0) | ((unsigned)f2bf(v.y + bc1) << 16);
            *(unsigned*)&sm.p2.abf[hh * 40 + lrow][lane * 2] = uo;
        }
        __syncthreads();                   // red free for next half / abf ready
    }

    // ===================== phase 3: fused MLP1 + colsum ====================
    // B frags direct global->reg (per-wave disjoint cols). No barriers.
    const short8* wl1 = (const short8*)Wl1_pk;
    short8 f0[8], f1[8];
    #pragma unroll
    for (int ks = 0; ks < 4; ks++)
        #pragma unroll
        for (int nt = 0; nt < 2; nt++)
            f0[ks * 2 + nt] = wl1[(ks * 8 + w * 2 + nt) * 64 + lane];
    #pragma unroll
    for (int ks = 0; ks < 4; ks++)
        #pragma unroll
        for (int nt = 0; nt < 2; nt++)
            f1[ks * 2 + nt] = wl1[2048 + (ks * 8 + w * 2 + nt) * 64 + lane];

    #pragma unroll
    for (int jb = 0; jb < 4; jb++) {
        floatx4 acc2[5][2] = {};
        const short8* fcur = (jb & 1) ? f1 : f0;   // compile-time (unrolled)
        #pragma unroll
        for (int ks = 0; ks < 4; ks++) {
            short8 bf0 = fcur[ks * 2 + 0];
            short8 bf1 = fcur[ks * 2 + 1];
            #pragma unroll
            for (int mt = 0; mt < 5; mt++) {
                short8 a = *(const short8*)&sm.p2.abf[mt * 16 + m][ks * 32 + q * 8];
                acc2[mt][0] = __builtin_amdgcn_mfma_f32_16x16x32_bf16(a, bf0, acc2[mt][0], 0, 0, 0);
                acc2[mt][1] = __builtin_amdgcn_mfma_f32_16x16x32_bf16(a, bf1, acc2[mt][1], 0, 0, 0);
            }
        }
        if (jb < 2) {
            short8* fnext = (jb & 1) ? f1 : f0;
            #pragma unroll
            for (int ks = 0; ks < 4; ks++)
                #pragma unroll
                for (int nt = 0; nt < 2; nt++)
                    fnext[ks * 2 + nt] = wl1[(size_t)(jb + 2) * 2048 + (ks * 8 + w * 2 + nt) * 64 + lane];
        }
        #pragma unroll
        for (int nt = 0; nt < 2; nt++) {
            int j = jb * 128 + w * 32 + nt * 16 + m;
            float blv = bl1[j];
            float vsum = 0.f;
            #pragma unroll
            for (int mt = 0; mt < 5; mt++)
                #pragma unroll
                for (int r = 0; r < 4; r++) {
                    float v = acc2[mt][nt][r] + blv;
                    vsum += v > 0.f ? v : 0.f;
                }
            vsum += __shfl_xor(vsum, 16, 64);
            vsum += __shfl_xor(vsum, 32, 64);
            if (q == 0) atomicAdd(&A_acc[(size_t)b * H1 + j], vsum);
        }
    }
}

// ------- final: out = A_acc @ Wl2 / 512 + bl2 * (400/512), 1 batch/block ---
__global__ __launch_bounds__(256) void final_out(
    const float* __restrict__ A_acc, const float* __restrict__ Wl2,
    const float* __restrict__ bl2, float* __restrict__ out)
{
    __shared__ float a[H1];
    int b = blockIdx.x, tid = threadIdx.x;
    a[tid] = A_acc[(size_t)b * H1 + tid];
    a[tid + 256] = A_acc[(size_t)b * H1 + tid + 256];
    __syncthreads();
    float acc = 0.f;
    #pragma unroll 8
    for (int k = 0; k < H1; k++)
        acc += a[k] * Wl2[(size_t)k * HS + tid];
    out[(size_t)b * HS + tid] = acc * (1.0f / 512.0f) + bl2[tid] * (400.0f / 512.0f);
}

extern "C" void kernel_launch(void* const* d_in, const int* in_sizes, int n_in,
                              void* d_out, int out_size, void* d_ws, size_t ws_size,
                              hipStream_t stream)
{
    const float* emb       = (const float*)d_in[0];
    const int*   x_tokens  = (const int*)d_in[1];
    // d_in[2..6]: edge_src/edge_dst DEAD; batch_ids/pos_ids arithmetic; mask analytic
    const float* emb_table = (const float*)d_in[7];
    // d_in[8..21]: W_e2g/b_e2g + all GAT params: DEAD
    const float* W_le = (const float*)d_in[22];
    const float* b_le = (const float*)d_in[23];
    const float* k7   = (const float*)d_in[24];
    const float* cb7  = (const float*)d_in[25];
    const float* k11  = (const float*)d_in[26];
    const float* cb11 = (const float*)d_in[27];
    const float* k15  = (const float*)d_in[28];
    const float* cb15 = (const float*)d_in[29];
    const float* Wl1  = (const float*)d_in[30];
    const float* bl1  = (const float*)d_in[31];
    const float* Wl2  = (const float*)d_in[32];
    const float* bl2  = (const float*)d_in[33];
    float* out = (float*)d_out;

    char* p = (char*)d_ws;
    unsigned short* Wpk = (unsigned short*)p;        p += (size_t)NTAP * HS * OC * 2;
    unsigned short* Wle_pk = (unsigned short*)p;     p += (size_t)KDIM * HS * 2;
    unsigned short* Wl1_pk = (unsigned short*)p;     p += (size_t)OC * H1 * 2;
    float* bcv = (float*)p;                          p += 512;
    float* A_acc = (float*)p;                        p += (size_t)NBATCH * H1 * 4;

    // setup: combine (1920) + Wle pack (640) + Wl1 pack (256) + A_acc (128)
    setup_all<<<dim3(2944), 256, 0, stream>>>(
        k7, k11, k15, cb7, cb11, cb15, W_le, Wl1,
        Wpk, bcv, Wle_pk, Wl1_pk, A_acc);
    fused_main<<<dim3(5, NBATCH), 256, 0, stream>>>(
        emb, x_tokens, emb_table, Wle_pk, b_le, Wpk, bcv, Wl1_pk, bl1, A_acc);
    final_out<<<NBATCH, 256, 0, stream>>>(A_acc, Wl2, bl2, out);
}